// Round 6
// baseline (712.488 us; speedup 1.0000x reference)
//
#include <hip/hip_runtime.h>

// ---------------------------------------------------------------------------
// GCN encoder, bf16 staging + MFMA GEMMs + XCD-sliced gather aggregation.
//   h  = relu(Agg(x@W1) + b1);  [mu|lv] = Agg(h@[Wmu|Wlv]) + bias
// Agg(p)[i] = dinv[i]*( sum_{e: dst=i} p[src]*dinv[src] + p[i]*dinv[i] )
// GEMM epilogues pre-scale rows by dinv and store q in SLICE-MAJOR layout
// (q[slice][node][16 feats], 8 slices of 3.2 MB). Aggregation runs one
// feature-slice per block with slice = blockIdx&7 -> each XCD's L2 holds one
// 3.2 MB slice (fits 4 MB), killing the 8x cross-XCD re-fetch (196 MB seen
// at R5 = 8 x 25.6 MB feature matrix).
// CSR build: LDS radix binning (R5), zero global atomics. n <= 131072.
// ---------------------------------------------------------------------------

#define C_IN  256
#define HID   128
#define C_OUT 64
#define NBUCK 1024
#define P1WGS 256

typedef __attribute__((ext_vector_type(8))) short bf16x8;
typedef __attribute__((ext_vector_type(4))) float f32x4;

__device__ inline unsigned short f2bf(float f) {  // round-to-nearest-even
  unsigned u = __float_as_uint(f);
  unsigned r = u + 0x7FFF + ((u >> 16) & 1);
  return (unsigned short)(r >> 16);
}
__device__ inline float bflo(unsigned v) { return __uint_as_float(v << 16); }
__device__ inline float bfhi(unsigned v) { return __uint_as_float(v & 0xFFFF0000u); }

// ---------------- P1: per-WG bucket histogram (LDS atomics only) -------------
__global__ __launch_bounds__(256) void k_bin_count(const int* __restrict__ dst,
                                                   int* __restrict__ histmat, int E) {
  __shared__ int h[NBUCK];
  int tid = threadIdx.x;
  for (int i = tid; i < NBUCK; i += 256) h[i] = 0;
  __syncthreads();
  for (int e = blockIdx.x * 256 + tid; e < E; e += P1WGS * 256)
    atomicAdd(&h[dst[e] >> 7], 1);
  __syncthreads();
  for (int i = tid; i < NBUCK; i += 256)
    histmat[blockIdx.x * NBUCK + i] = h[i];
}

// ---------------- P2: per-bucket exclusive scan across WGs (in place) --------
__global__ __launch_bounds__(256) void k_col_scan(int* __restrict__ histmat,
                                                  int* __restrict__ bucket_tot) {
  __shared__ int sh[P1WGS];
  int b = blockIdx.x;
  int t = threadIdx.x;
  int v = histmat[t * NBUCK + b];
  sh[t] = v; __syncthreads();
  for (int ofs = 1; ofs < P1WGS; ofs <<= 1) {
    int add = (t >= ofs) ? sh[t - ofs] : 0;
    __syncthreads();
    sh[t] += add;
    __syncthreads();
  }
  histmat[t * NBUCK + b] = sh[t] - v;  // exclusive
  if (t == P1WGS - 1) bucket_tot[b] = sh[t];
}

// ---------------- P3: bucket_start = exclusive scan of bucket_tot ------------
__global__ void k_bucket_scan(const int* __restrict__ bucket_tot,
                              int* __restrict__ bucket_start, int E) {
  __shared__ int sh[NBUCK];
  int t = threadIdx.x;
  int v = bucket_tot[t];
  sh[t] = v; __syncthreads();
  for (int ofs = 1; ofs < NBUCK; ofs <<= 1) {
    int add = (t >= ofs) ? sh[t - ofs] : 0;
    __syncthreads();
    sh[t] += add;
    __syncthreads();
  }
  bucket_start[t] = sh[t] - v;
  if (t == NBUCK - 1) bucket_start[NBUCK] = E;
}

// ---------------- P4: scatter edges into bucket-segmented array --------------
__global__ __launch_bounds__(256) void k_bin_scatter(const int* __restrict__ src,
                                                     const int* __restrict__ dst,
                                                     const int* __restrict__ histmat,
                                                     const int* __restrict__ bucket_start,
                                                     unsigned* __restrict__ binned, int E) {
  __shared__ int cur[NBUCK];
  int tid = threadIdx.x;
  for (int i = tid; i < NBUCK; i += 256)
    cur[i] = bucket_start[i] + histmat[blockIdx.x * NBUCK + i];
  __syncthreads();
  for (int e = blockIdx.x * 256 + tid; e < E; e += P1WGS * 256) {
    int d = dst[e];
    int pos = atomicAdd(&cur[d >> 7], 1);
    binned[pos] = (unsigned)src[e] | ((unsigned)(d & 127) << 17);
  }
}

// ---------------- P5: per-bucket deg/dinv/row_start + CSR fill ---------------
__global__ __launch_bounds__(256) void k_bucket_csr(const unsigned* __restrict__ binned,
                                                    const int* __restrict__ bucket_start,
                                                    int* __restrict__ row_start,
                                                    float* __restrict__ dinv,
                                                    int* __restrict__ csr_src,
                                                    int n, int E) {
  __shared__ int h[128], ls[128], c[128];
  int b = blockIdx.x, t = threadIdx.x;
  int start = bucket_start[b], end = bucket_start[b + 1];
  if (t < 128) h[t] = 0;
  __syncthreads();
  for (int e = start + t; e < end; e += 256)
    atomicAdd(&h[binned[e] >> 17], 1);
  __syncthreads();
  if (t < 128) ls[t] = h[t];
  __syncthreads();
  for (int ofs = 1; ofs < 128; ofs <<= 1) {
    int add = (t < 128 && t >= ofs) ? ls[t - ofs] : 0;
    __syncthreads();
    if (t < 128) ls[t] += add;
    __syncthreads();
  }
  if (t < 128) {
    int excl = ls[t] - h[t];
    c[t] = excl;
    int node = b * 128 + t;
    if (node < n) {
      row_start[node] = start + excl;
      dinv[node] = rsqrtf((float)h[t] + 1.0f);
    }
  }
  if (b == 0 && t == 0) row_start[n] = E;
  __syncthreads();
  for (int e = start + t; e < end; e += 256) {
    unsigned v = binned[e];
    int pos = start + atomicAdd(&c[v >> 17], 1);
    csr_src[pos] = (int)(v & 0x1FFFF);
  }
}

// ---------------- weight pre-swizzle into MFMA fragment order ----------------
__global__ void k_prep(const float* __restrict__ W1, const float* __restrict__ Wmu,
                       const float* __restrict__ Wlv,
                       unsigned short* __restrict__ bswz1,
                       unsigned short* __restrict__ bswz2) {
  int idx = blockIdx.x * 256 + threadIdx.x;
  if (idx < 4096) {            // W1: (256/32)*8*64
    int L = idx & 63, t = (idx >> 6) & 7, s = idx >> 9;
    const float* srcp = W1 + (size_t)(s * 32 + ((L >> 4) << 3)) * 128 + t * 16 + (L & 15);
    unsigned short* dstp = bswz1 + (size_t)idx * 8;
#pragma unroll
    for (int j = 0; j < 8; j++) dstp[j] = f2bf(srcp[(size_t)j * 128]);
  } else if (idx < 6144) {     // [Wmu|Wlv]: (128/32)*8*64
    int id2 = idx - 4096;
    int L = id2 & 63, t = (id2 >> 6) & 7, s = id2 >> 9;
    int nn = t * 16 + (L & 15);
    int k0 = s * 32 + ((L >> 4) << 3);
    const float* W = (nn < C_OUT) ? (Wmu + nn) : (Wlv + (nn - C_OUT));
    unsigned short* dstp = bswz2 + (size_t)id2 * 8;
#pragma unroll
    for (int j = 0; j < 8; j++) dstp[j] = f2bf(W[(size_t)(k0 + j) * C_OUT]);
  }
}

// ---- MFMA GEMM: q[slice][node][16] = dinv[node] * (A[M,K] @ B[K,128]) -------
// Output slice-major, pre-scaled by dinv (agg then needs no per-edge weight).
template <typename AT, int K>
__global__ __launch_bounds__(256) void k_gemm_mfma(const AT* __restrict__ A,
                                                   const unsigned short* __restrict__ bswz,
                                                   const float* __restrict__ dscale,
                                                   unsigned short* __restrict__ q,
                                                   int M) {
  constexpr int NS = K / 32;
  int wave = threadIdx.x >> 6, lane = threadIdx.x & 63;
  int m0 = blockIdx.x * 64 + wave * 16;
  int lrow = lane & 15, lq = lane >> 4;
  int arow = m0 + lrow;
  bool rv = arow < M;
  const AT* ap = A + (size_t)(rv ? arow : 0) * K + lq * 8;

  auto loadA = [&](int s) -> bf16x8 {
    if (sizeof(AT) == 4) {
      const float* af = (const float*)ap + s * 32;
      float4 u0 = rv ? *(const float4*)(af) : float4{0, 0, 0, 0};
      float4 u1 = rv ? *(const float4*)(af + 4) : float4{0, 0, 0, 0};
      union { unsigned short us[8]; bf16x8 v; } tmp;
      tmp.us[0] = f2bf(u0.x); tmp.us[1] = f2bf(u0.y);
      tmp.us[2] = f2bf(u0.z); tmp.us[3] = f2bf(u0.w);
      tmp.us[4] = f2bf(u1.x); tmp.us[5] = f2bf(u1.y);
      tmp.us[6] = f2bf(u1.z); tmp.us[7] = f2bf(u1.w);
      return tmp.v;
    } else {
      const unsigned short* ab = (const unsigned short*)ap + s * 32;
      return rv ? *(const bf16x8*)(ab) : (bf16x8)(short)0;
    }
  };

  f32x4 acc[8];
#pragma unroll
  for (int t = 0; t < 8; t++) acc[t] = (f32x4){0.f, 0.f, 0.f, 0.f};

  bf16x8 a_cur = loadA(0);
  bf16x8 b_cur[8];
#pragma unroll
  for (int t = 0; t < 8; t++)
    b_cur[t] = *(const bf16x8*)(bswz + lane * 8 + t * 512);

#pragma unroll
  for (int s = 0; s < NS; ++s) {
    bf16x8 a_nxt = a_cur;
    bf16x8 b_nxt[8];
    if (s + 1 < NS) {
      a_nxt = loadA(s + 1);
      const unsigned short* bp = bswz + (size_t)(s + 1) * 4096 + lane * 8;
#pragma unroll
      for (int t = 0; t < 8; t++) b_nxt[t] = *(const bf16x8*)(bp + t * 512);
    }
#pragma unroll
    for (int t = 0; t < 8; t++)
      acc[t] = __builtin_amdgcn_mfma_f32_16x16x32_bf16(a_cur, b_cur[t], acc[t], 0, 0, 0);
    a_cur = a_nxt;
    if (s + 1 < NS) {
#pragma unroll
      for (int t = 0; t < 8; t++) b_cur[t] = b_nxt[t];
    }
  }
#pragma unroll
  for (int i = 0; i < 4; i++) {
    int rr = m0 + lq * 4 + i;
    if (rr < M) {
      float sc = dscale[rr];
#pragma unroll
      for (int t = 0; t < 8; t++)   // slice t, feat lrow
        q[((size_t)t * M + rr) * 16 + lrow] = f2bf(acc[t][i] * sc);
    }
  }
}

// ---------------- sliced gather aggregation ----------------------------------
// Block: slice = blockIdx&7 (XCD-pinned), 4 waves = 4 nodes.
// Lane = group g (lane>>3) x feat-dword f (lane&7): 16 edges/iter (unroll 2),
// 16 feats per edge. Terms t in [0, deg]: t<deg -> csr edge, t==deg -> self.
#define AGG_SLICE_BODY                                                              \
  int slice = blockIdx.x & 7;                                                       \
  int wave = threadIdx.x >> 6;                                                      \
  int wid = (blockIdx.x >> 3) * 4 + wave;                                           \
  if (wid >= n) return;                                                             \
  int lane = threadIdx.x & 63;                                                      \
  int g = lane >> 3, f = lane & 7;                                                  \
  int rs = row_start[wid];                                                          \
  int deg = row_start[wid + 1] - rs;                                                \
  const unsigned short* qs = q + (size_t)slice * n * 16;                            \
  float a0 = 0.f, a1 = 0.f;                                                         \
  for (int t0 = 0; t0 <= deg; t0 += 16) {                                           \
    int i0 = t0 + g, i1 = t0 + 8 + g;                                               \
    int s0 = (i0 < deg) ? csr[rs + i0] : wid;                                       \
    int s1 = (i1 < deg) ? csr[rs + i1] : wid;                                       \
    unsigned v0 = *(const unsigned*)(qs + (size_t)s0 * 16 + f * 2);                 \
    unsigned v1 = *(const unsigned*)(qs + (size_t)s1 * 16 + f * 2);                 \
    if (i0 > deg) v0 = 0;                                                           \
    if (i1 > deg) v1 = 0;                                                           \
    a0 += bflo(v0); a1 += bfhi(v0);                                                 \
    a0 += bflo(v1); a1 += bfhi(v1);                                                 \
  }                                                                                 \
  a0 += __shfl_xor(a0, 8);  a1 += __shfl_xor(a1, 8);                                \
  a0 += __shfl_xor(a0, 16); a1 += __shfl_xor(a1, 16);                               \
  a0 += __shfl_xor(a0, 32); a1 += __shfl_xor(a1, 32);                               \
  float di = dinv[wid];

__global__ __launch_bounds__(256) void k_agg_relu_sl(
    const unsigned short* __restrict__ q, const float* __restrict__ dinv,
    const int* __restrict__ row_start, const int* __restrict__ csr,
    const float* __restrict__ bias, unsigned short* __restrict__ h, int n) {
  AGG_SLICE_BODY
  if (g == 0) {  // lanes 0-7 hold feats slice*16 + 2f, 2f+1
    float2 bb = *(const float2*)(bias + slice * 16 + 2 * f);
    float r0 = fmaxf(a0 * di + bb.x, 0.f);
    float r1 = fmaxf(a1 * di + bb.y, 0.f);
    unsigned pk = (unsigned)f2bf(r0) | ((unsigned)f2bf(r1) << 16);
    *(unsigned*)(h + (size_t)wid * 128 + slice * 16 + 2 * f) = pk;  // row-major
  }
}

__global__ __launch_bounds__(256) void k_agg_out_sl(
    const unsigned short* __restrict__ q, const float* __restrict__ dinv,
    const int* __restrict__ row_start, const int* __restrict__ csr,
    const float* __restrict__ bmu, const float* __restrict__ blv,
    float* __restrict__ out, int n) {
  AGG_SLICE_BODY
  if (g == 0) {
    // slices 0-3 -> mu cols, 4-7 -> lv cols
    int c0 = (slice & 3) * 16 + 2 * f;
    float2 bb = (slice < 4) ? *(const float2*)(bmu + c0)
                            : *(const float2*)(blv + c0);
    float* op = (slice < 4) ? (out + (size_t)wid * C_OUT + c0)
                            : (out + (size_t)(n + wid) * C_OUT + c0);
    float2 res = {a0 * di + bb.x, a1 * di + bb.y};
    *(float2*)op = res;
  }
}

// ---------------------------------------------------------------------------
extern "C" void kernel_launch(void* const* d_in, const int* in_sizes, int n_in,
                              void* d_out, int out_size, void* d_ws, size_t ws_size,
                              hipStream_t stream) {
  const float* x   = (const float*)d_in[0];
  const int*   ei  = (const int*)d_in[1];   // int32 on the wire (JAX x64 off)
  const float* W1  = (const float*)d_in[2];
  const float* b1  = (const float*)d_in[3];
  const float* Wmu = (const float*)d_in[4];
  const float* bmu = (const float*)d_in[5];
  const float* Wlv = (const float*)d_in[6];
  const float* blv = (const float*)d_in[7];
  float* out = (float*)d_out;

  const int n = in_sizes[0] / C_IN;
  const int E = in_sizes[1] / 2;
  const int* src = ei;
  const int* dst = ei + E;

  char* w = (char*)d_ws;
  auto alloc = [&](size_t bytes) -> void* {
    void* pp = (void*)w;
    w += (bytes + 255) & ~(size_t)255;
    return pp;
  };
  float*          dinv       = (float*)alloc((size_t)n * 4);
  int*            row_start  = (int*)alloc((size_t)(n + 1) * 4);
  int*            histmat    = (int*)alloc((size_t)P1WGS * NBUCK * 4);
  int*            bucket_tot = (int*)alloc((size_t)NBUCK * 4);
  int*            bucket_st  = (int*)alloc((size_t)(NBUCK + 1) * 4);
  unsigned*       binned     = (unsigned*)alloc((size_t)E * 4);
  int*            csr_src    = (int*)alloc((size_t)E * 4);
  unsigned short* bswz1      = (unsigned short*)alloc((size_t)C_IN * 128 * 2);
  unsigned short* bswz2      = (unsigned short*)alloc((size_t)HID * 128 * 2);
  unsigned short* q1         = (unsigned short*)alloc((size_t)n * 128 * 2);  // slice-major
  unsigned short* hbuf       = (unsigned short*)alloc((size_t)n * 128 * 2);  // row-major
  unsigned short* q2         = (unsigned short*)alloc((size_t)n * 128 * 2);  // slice-major
  (void)ws_size; (void)n_in; (void)out_size;

  const int TB = 256;
  const int gemm_bks = (n + 63) / 64;
  const int agg_bks = ((n + 3) / 4) * 8;      // 4 nodes/block x 8 slices
  const int nbk_csr = (n + 127) / 128;

  // ---- CSR build: LDS radix binning, no global atomics ----
  k_bin_count<<<P1WGS, TB, 0, stream>>>(dst, histmat, E);
  k_col_scan<<<NBUCK, TB, 0, stream>>>(histmat, bucket_tot);
  k_bucket_scan<<<1, NBUCK, 0, stream>>>(bucket_tot, bucket_st, E);
  k_bin_scatter<<<P1WGS, TB, 0, stream>>>(src, dst, histmat, bucket_st, binned, E);
  k_bucket_csr<<<nbk_csr, TB, 0, stream>>>(binned, bucket_st, row_start, dinv,
                                           csr_src, n, E);

  // ---- weight pre-swizzle ----
  k_prep<<<24, 256, 0, stream>>>(W1, Wmu, Wlv, bswz1, bswz2);

  // ---- layer 1 ----
  k_gemm_mfma<float, C_IN><<<gemm_bks, TB, 0, stream>>>(x, bswz1, dinv, q1, n);
  k_agg_relu_sl<<<agg_bks, TB, 0, stream>>>(q1, dinv, row_start, csr_src, b1, hbuf, n);

  // ---- layer 2+3 fused ----
  k_gemm_mfma<unsigned short, HID><<<gemm_bks, TB, 0, stream>>>(hbuf, bswz2, dinv, q2, n);
  k_agg_out_sl<<<agg_bks, TB, 0, stream>>>(q2, dinv, row_start, csr_src, bmu, blv, out, n);
}